// Round 15
// baseline (145.501 us; speedup 1.0000x reference)
//
#include <hip/hip_runtime.h>

typedef __attribute__((ext_vector_type(8))) short short8;
typedef __attribute__((ext_vector_type(4))) float f32x4;
typedef __attribute__((ext_vector_type(16))) float f32x16;
typedef __attribute__((ext_vector_type(4))) float float4v;
typedef __attribute__((ext_vector_type(8))) float f32x8;
typedef __attribute__((ext_vector_type(4))) unsigned short us4;
typedef __attribute__((ext_vector_type(8))) unsigned short us8v;
typedef __attribute__((ext_vector_type(4))) unsigned int uint4v;

#define DEVI __device__ __forceinline__
#define MFMA16(a,b,c) __builtin_amdgcn_mfma_f32_16x16x32_bf16((a),(b),(c),0,0,0)
#define MFMA32(a,b,c) __builtin_amdgcn_mfma_f32_32x32x16_bf16((a),(b),(c),0,0,0)

// ---------- helpers ----------
DEVI unsigned short f2bf(float x) {            // f32 -> bf16 bits, RNE
    unsigned u = __builtin_bit_cast(unsigned, x);
    u += 0x7FFFu + ((u >> 16) & 1u);
    return (unsigned short)(u >> 16);
}
DEVI float bf2f(unsigned short b) {
    return __builtin_bit_cast(float, ((unsigned)b) << 16);
}
DEVI unsigned cvt_pk_bf16(float lo, float hi) {  // lo -> low16, hi -> high16 (RNE)
    unsigned r;
    asm("v_cvt_pk_bf16_f32 %0, %1, %2" : "=v"(r) : "v"(lo), "v"(hi));
    return r;
}

// ---------- prep: hidden f32 -> bf16 hi/lo in MFMA-fragment tile order ----------
// htiles[rt 0..63][kt 0..15][i 0..3][lane 0..63][8]:
//   content = hidden[rt*64 + i*16 + (lane&15)][kt*32 + (lane>>4)*8 + j]
__global__ __launch_bounds__(256) void k_prep_hidden(const float* __restrict__ hid,
                                                     unsigned short* __restrict__ hh,
                                                     unsigned short* __restrict__ hl) {
    __shared__ float tile[64][65];
    const int bid = blockIdx.x;                 // 512 = 64 rt x 8 ct
    const int rt = bid >> 3, ct = bid & 7;
    const int t = threadIdx.x;
    const int r = t >> 2, cc = (t & 3) << 4;
    const float* sp = hid + (long)(rt * 64 + r) * 512 + ct * 64 + cc;
    #pragma unroll
    for (int j = 0; j < 16; j += 4) {
        float4v v = *reinterpret_cast<const float4v*>(sp + j);
        tile[r][cc + j + 0] = v[0];
        tile[r][cc + j + 1] = v[1];
        tile[r][cc + j + 2] = v[2];
        tile[r][cc + j + 3] = v[3];
    }
    __syncthreads();
    #pragma unroll
    for (int s = 0; s < 2; ++s) {
        int slot = t * 2 + s;                   // 0..511 -> (ktl, i, lane)
        int lane = slot & 63, i = (slot >> 6) & 3, ktl = slot >> 8;
        int ri = i * 16 + (lane & 15);
        int kc = ktl * 32 + (lane >> 4) * 8;
        us8v hv, lv;
        #pragma unroll
        for (int j = 0; j < 8; ++j) {
            float x = tile[ri][kc + j];
            unsigned short hb = f2bf(x);
            hv[j] = hb; lv[j] = f2bf(x - bf2f(hb));
        }
        long o = ((long)(rt * 16 + ct * 2 + ktl) * 4 + i) * 512 + lane * 8;
        *reinterpret_cast<us8v*>(hh + o) = hv;
        *reinterpret_cast<us8v*>(hl + o) = lv;
    }
}

// ---------- prep: transpose weights; ALL mats in fragment-tile order ----------
// wtiles[nt 0..7][kt 0..15][jj 0..3][lane][8]:
//   content = W^T[nt*64 + jj*16 + (lane&15)][kt*32 + (lane>>4)*8 + j]
__global__ __launch_bounds__(256) void k_prep_w(const float* __restrict__ wq, const float* __restrict__ wk,
                                                const float* __restrict__ wvp, const float* __restrict__ wo,
                                                unsigned short* __restrict__ wqthi, unsigned short* __restrict__ wqtlo,
                                                unsigned short* __restrict__ wkthi, unsigned short* __restrict__ wktlo,
                                                unsigned short* __restrict__ wvt, unsigned short* __restrict__ wot) {
    __shared__ float tile[64][65];
    const int bid = blockIdx.x;                 // 256 = 4 mats x 64 tiles
    const int mat = bid >> 6, t6 = bid & 63;
    const int tr = t6 >> 3, tc = t6 & 7;        // source tile coords: [k-tile][n-tile]
    const float* src = mat == 0 ? wq : mat == 1 ? wk : mat == 2 ? wvp : wo;
    const int t = threadIdx.x;
    const int r = t >> 2, cc = (t & 3) << 4;
    const float* sp = src + (long)(tr * 64 + r) * 512 + tc * 64 + cc;
    #pragma unroll
    for (int j = 0; j < 16; j += 4) {
        float4v v = *reinterpret_cast<const float4v*>(sp + j);
        tile[r][cc + j + 0] = v[0];
        tile[r][cc + j + 1] = v[1];
        tile[r][cc + j + 2] = v[2];
        tile[r][cc + j + 3] = v[3];
    }
    __syncthreads();
    // thread owns n = tc*64 + r ; k = tr*64 + cc + 0..16
    us8v h0, h1, l0, l1;
    #pragma unroll
    for (int j = 0; j < 8; ++j) {
        float x = tile[cc + j][r];
        unsigned short hb = f2bf(x);
        h0[j] = hb; l0[j] = f2bf(x - bf2f(hb));
        float y = tile[cc + 8 + j][r];
        unsigned short hb2 = f2bf(y);
        h1[j] = hb2; l1[j] = f2bf(y - bf2f(hb2));
    }
    const int jj = r >> 4, li = r & 15;
    const int kt = (tr * 64 + cc) >> 5;
    const int g0 = (cc >> 3) & 3;           // 0 or 2
    const long bse = ((long)((tc * 16 + kt) * 4 + jj)) * 512;
    const long o0 = bse + (g0 * 16 + li) * 8;
    const long o1 = bse + ((g0 + 1) * 16 + li) * 8;
    if (mat <= 1) {
        unsigned short* oh = mat ? wkthi : wqthi;
        unsigned short* ol = mat ? wktlo : wqtlo;
        *reinterpret_cast<us8v*>(oh + o0) = h0;
        *reinterpret_cast<us8v*>(oh + o1) = h1;
        *reinterpret_cast<us8v*>(ol + o0) = l0;
        *reinterpret_cast<us8v*>(ol + o1) = l1;
    } else {
        unsigned short* oh = mat == 2 ? wvt : wot;
        *reinterpret_cast<us8v*>(oh + o0) = h0;
        *reinterpret_cast<us8v*>(oh + o1) = h1;
    }
}

// ---------- prep: bias table biasT[h][rel+2047] ----------
DEVI int bucket_large(int a) {   // exact integer thresholds of 8+floor(2*log2(a/8)), clamp 15
    if (a < 12) return 8;
    if (a < 16) return 9;
    if (a < 23) return 10;
    if (a < 32) return 11;
    if (a < 46) return 12;
    if (a < 64) return 13;
    if (a < 91) return 14;
    return 15;
}
__global__ __launch_bounds__(256) void k_prep_bias(const float* __restrict__ emb, float* __restrict__ biasT) {
    int t = blockIdx.x * 256 + threadIdx.x;
    if (t >= 8 * 4095) return;
    int h = t / 4095;
    int idx = t - h * 4095;
    int rel = idx - 2047;                // rel = k - q
    int a = rel < 0 ? -rel : rel;
    int bucket = (rel > 0 ? 16 : 0) + (a < 8 ? a : bucket_large(a));
    biasT[h * 4096 + idx] = emb[bucket * 8 + h];
}

// ---------- fused QKV projection; fragment-tiled A/B loads, K/V fragment-tile outputs ----------
__global__ __launch_bounds__(256) void k_proj(const unsigned short* __restrict__ hh,
                                              const unsigned short* __restrict__ hl,
                                              const unsigned short* __restrict__ wqthi, const unsigned short* __restrict__ wqtlo,
                                              const unsigned short* __restrict__ wkthi, const unsigned short* __restrict__ wktlo,
                                              const unsigned short* __restrict__ wvt,
                                              unsigned short* __restrict__ q_hi, unsigned short* __restrict__ q_lo,
                                              unsigned short* __restrict__ ktiles,
                                              unsigned short* __restrict__ vtiles) {
    // XCD-aware swizzle (T1): 384 = 8 XCDs x 48 consecutive logical blocks
    const int wgid = (blockIdx.x & 7) * 48 + (blockIdx.x >> 3);
    const int nt = wgid % 12, mt = wgid / 12;
    const int sec = nt >> 2;                // 0:Q 1:K 2:V
    const bool isv = (sec == 2);
    const int tid = threadIdx.x, wv = tid >> 6, lane = tid & 63;
    const int wr = wv >> 1, wc = wv & 1;
    const int g = lane >> 4, li = lane & 15;
    const int m0 = mt * 128 + wr * 64;
    const int n0 = (nt & 3) * 128 + wc * 64;    // col within section [0,512)
    const unsigned short* bh_ = (sec == 0) ? wqthi : (sec == 1) ? wkthi : wvt;
    const unsigned short* bl_ = (sec == 0) ? wqtlo : wktlo;
    const int rt2 = m0 >> 6;                 // A row-tile
    const int ntile = n0 >> 6;               // B n-tile within section

    f32x4 zf = {0.f, 0.f, 0.f, 0.f};
    f32x4 acc[4][4];
    #pragma unroll
    for (int i = 0; i < 4; ++i)
        #pragma unroll
        for (int j = 0; j < 4; ++j) acc[i][j] = zf;

    for (int ks = 0; ks < 512; ks += 32) {
        const int kt = ks >> 5;
        const long abase = ((long)(rt2 * 16 + kt) * 4) * 512 + lane * 8;
        const long bbase = ((long)(ntile * 16 + kt) * 4) * 512 + lane * 8;
        short8 ah[4], al[4], bhf[4], blf[4];
        #pragma unroll
        for (int i = 0; i < 4; ++i) {
            ah[i] = *reinterpret_cast<const short8*>(hh + abase + i * 512);
            if (!isv) al[i] = *reinterpret_cast<const short8*>(hl + abase + i * 512);
            bhf[i] = *reinterpret_cast<const short8*>(bh_ + bbase + i * 512);
            if (!isv) blf[i] = *reinterpret_cast<const short8*>(bl_ + bbase + i * 512);
        }
        #pragma unroll
        for (int i = 0; i < 4; ++i)
            #pragma unroll
            for (int j = 0; j < 4; ++j) {
                acc[i][j] = MFMA16(ah[i], bhf[j], acc[i][j]);
                if (!isv) {
                    acc[i][j] = MFMA16(ah[i], blf[j], acc[i][j]);
                    acc[i][j] = MFMA16(al[i], bhf[j], acc[i][j]);
                }
            }
    }

    if (sec == 0) {
        #pragma unroll
        for (int i = 0; i < 4; ++i) {
            int rowb = m0 + i * 16 + g * 4;
            #pragma unroll
            for (int j = 0; j < 4; ++j) {
                int col = n0 + j * 16 + li;
                #pragma unroll
                for (int r = 0; r < 4; ++r) {
                    float x = acc[i][j][r];
                    unsigned short hb = f2bf(x);
                    long o = (long)(rowb + r) * 512 + col;
                    q_hi[o] = hb;
                    q_lo[o] = f2bf(x - bf2f(hb));
                }
            }
        }
    } else if (sec == 1) {
        #pragma unroll
        for (int i = 0; i < 4; ++i) {
            int rowb = m0 + i * 16 + g * 4;
            #pragma unroll
            for (int j = 0; j < 4; ++j) {
                int col = n0 + j * 16 + li;
                int h2 = col >> 6, d = col & 63;
                int ds2 = d >> 4, j2 = d & 7, lhalf = (d >> 3) & 1;
                #pragma unroll
                for (int r = 0; r < 4; ++r) {
                    int srow = rowb + r;
                    int bloc = srow >> 11, k = srow & 2047;
                    long base = (long)((bloc * 8 + h2) * 64 + (k >> 5)) * 4096
                              + (((k & 31) | (lhalf << 5)) * 8 + j2);
                    float x = acc[i][j][r];
                    unsigned short hb = f2bf(x);
                    ktiles[base + ds2 * 512] = hb;
                    ktiles[base + (4 + ds2) * 512] = f2bf(x - bf2f(hb));
                }
            }
        }
    } else {
        #pragma unroll
        for (int i = 0; i < 4; ++i) {
            int rowb = m0 + i * 16 + g * 4;      // 4 consecutive k, same tile/half
            int bloc = rowb >> 11, k = rowb & 2047;
            int kt = k >> 5, t = (k >> 4) & 1, lhalf = (k >> 3) & 1, j0 = k & 7;
            #pragma unroll
            for (int j = 0; j < 4; ++j) {
                int col = n0 + j * 16 + li;
                int h2 = col >> 6, d = col & 63;
                int dblk = d >> 5;
                us4 w;
                #pragma unroll
                for (int r = 0; r < 4; ++r) w[r] = f2bf(acc[i][j][r]);
                long off2 = (long)((bloc * 8 + h2) * 64 + kt) * 2048
                          + (dblk * 2 + t) * 512 + (((d & 31) | (lhalf << 5)) * 8 + j0);
                *reinterpret_cast<us4*>(vtiles + off2) = w;
            }
        }
    }
}

// ---------- flash attention + fused position_bias writer ----------
// grid 1024 = 16 bh * 64 q-tiles(32 rows). block 128 = 2 waves: kh = k-half.
// XCD-aware swizzle: each XCD owns 128 consecutive logical blocks = 2 bh (K/V set 1.5MB fits L2).
__global__ __launch_bounds__(128) void k_attn(const unsigned short* __restrict__ qhi,
                                              const unsigned short* __restrict__ qlo,
                                              const unsigned short* __restrict__ ktiles,
                                              const unsigned short* __restrict__ vtiles,
                                              const float* __restrict__ biasT,
                                              unsigned short* __restrict__ ctx,
                                              float* __restrict__ outb) {
    __shared__ float lb[2080];
    __shared__ float mrg[64][34];
    const int wg = ((blockIdx.x & 7) << 7) | (blockIdx.x >> 3);   // T1 swizzle (1024 = 8*128)
    const int bh = wg >> 6, qt = wg & 63;
    const int b = bh >> 3, h = bh & 7;
    const int tid = threadIdx.x;
    const int kh = tid >> 6, lane = tid & 63;
    const int ql_ = lane & 31, hi = lane >> 5;
    const int q0 = qt * 32;

    // bias window: lb[i] = biasT[h][2016 - q0 + i]; in-loop index = k - ql_ + 31
    for (int i = tid; i < 2080; i += 128) lb[i] = biasT[h * 4096 + (2016 - q0) + i];
    __syncthreads();

    const int q = q0 + ql_;
    const long rowQ = (long)(b * 2048 + q) * 512 + h * 64 + hi * 8;
    short8 qfh[4], qfl[4];
    #pragma unroll
    for (int ds = 0; ds < 4; ++ds) {
        qfh[ds] = *reinterpret_cast<const short8*>(qhi + rowQ + ds * 16);
        qfl[ds] = *reinterpret_cast<const short8*>(qlo + rowQ + ds * 16);
    }
    const int kbeg = kh * 1024;
    const unsigned short* ktb = ktiles + ((long)bh * 64 + (kbeg >> 5)) * 4096;
    const unsigned short* vtb = vtiles + ((long)bh * 64 + (kbeg >> 5)) * 2048;

    f32x16 o0, o1;
    #pragma unroll
    for (int i = 0; i < 16; ++i) { o0[i] = 0.f; o1[i] = 0.f; }
    float m_run = -__builtin_inff(), l_run = 0.f;

    // register double buffers (prefetch tile 0)
    short8 kAh[4], kAl[4], kBh[4], kBl[4], vA[4], vB[4];
    #pragma unroll
    for (int ds = 0; ds < 4; ++ds) {
        kAh[ds] = *reinterpret_cast<const short8*>(ktb + ds * 512 + lane * 8);
        kAl[ds] = *reinterpret_cast<const short8*>(ktb + (4 + ds) * 512 + lane * 8);
    }
    #pragma unroll
    for (int i = 0; i < 4; ++i)
        vA[i] = *reinterpret_cast<const short8*>(vtb + i * 512 + lane * 8);

    auto step = [&](short8 (&ckh)[4], short8 (&ckl)[4], short8 (&cv)[4],
                    short8 (&nkh)[4], short8 (&nkl)[4], short8 (&nv)[4], int it) {
        // QK^T (two independent chains, pure reassociation)
        f32x16 ssA, ssB;
        #pragma unroll
        for (int i = 0; i < 16; ++i) { ssA[i] = 0.f; ssB[i] = 0.f; }
        __builtin_amdgcn_s_setprio(1);
        #pragma unroll
        for (int ds = 0; ds < 4; ++ds) {
            ssA = MFMA32(ckh[ds], qfh[ds], ssA);
            ssB = MFMA32(ckh[ds], qfl[ds], ssB);
        }
        #pragma unroll
        for (int ds = 0; ds < 4; ++ds)
            ssA = MFMA32(ckl[ds], qfh[ds], ssA);
        __builtin_amdgcn_s_setprio(0);
        // prefetch next tile (coalesced 1KB bursts; guarded re-read on last iter)
        const long ko = (it + 1 < 32) ? (long)(it + 1) * 4096 : (long)it * 4096;
        const long vo = (it + 1 < 32) ? (long)(it + 1) * 2048 : (long)it * 2048;
        #pragma unroll
        for (int ds = 0; ds < 4; ++ds) {
            nkh[ds] = *reinterpret_cast<const short8*>(ktb + ko + ds * 512 + lane * 8);
            nkl[ds] = *reinterpret_cast<const short8*>(ktb + ko + (4 + ds) * 512 + lane * 8);
        }
        #pragma unroll
        for (int i = 0; i < 4; ++i)
            nv[i] = *reinterpret_cast<const short8*>(vtb + vo + i * 512 + lane * 8);
        // bias + row softmax (row = q, all in-lane except one hi-swap)
        const int k0 = kbeg + it * 32;
        const int ib = k0 - ql_ + 31 + 4 * hi;
        float s[16];
        #pragma unroll
        for (int r = 0; r < 16; ++r)
            s[r] = (ssA[r] + ssB[r]) + lb[ib + (r & 3) + 8 * (r >> 2)];
        // max tree (depth 4)
        float t0 = fmaxf(s[0], s[1]), t1 = fmaxf(s[2], s[3]), t2 = fmaxf(s[4], s[5]), t3 = fmaxf(s[6], s[7]);
        float t4 = fmaxf(s[8], s[9]), t5 = fmaxf(s[10], s[11]), t6 = fmaxf(s[12], s[13]), t7 = fmaxf(s[14], s[15]);
        float u0 = fmaxf(t0, t1), u1 = fmaxf(t2, t3), u2 = fmaxf(t4, t5), u3 = fmaxf(t6, t7);
        float mx = fmaxf(fmaxf(u0, u1), fmaxf(u2, u3));
        mx = fmaxf(mx, __shfl_xor(mx, 32));
        bool grown = mx > m_run;
        float mnew = fmaxf(m_run, mx);
        float scale = __expf(m_run - mnew);
        float p[16];
        #pragma unroll
        for (int r = 0; r < 16; ++r) p[r] = __expf(s[r] - mnew);
        // pack via cvt_pk (RNE); denominator from the SAME rounded bits
        unsigned W[8];
        float ps[8];
        #pragma unroll
        for (int r2 = 0; r2 < 8; ++r2) {
            unsigned w = cvt_pk_bf16(p[2 * r2], p[2 * r2 + 1]);
            W[r2] = w;
            float plo = __builtin_bit_cast(float, w << 16);
            float phi = __builtin_bit_cast(float, w & 0xFFFF0000u);
            ps[r2] = plo + phi;
        }
        float psum = ((ps[0] + ps[1]) + (ps[2] + ps[3])) + ((ps[4] + ps[5]) + (ps[6] + ps[7]));
        l_run = l_run * scale + psum;
        m_run = mnew;
        // defer-rescale: when no row max grew, scale == 1.0 exactly -> skip is bit-identical
        if (__any(grown)) {
            #pragma unroll
            for (int i = 0; i < 16; ++i) { o0[i] *= scale; o1[i] *= scale; }
        }
        unsigned Sw[8];
        #pragma unroll
        for (int r2 = 0; r2 < 8; ++r2) Sw[r2] = __shfl_xor(W[r2], 32);
        __builtin_amdgcn_s_setprio(1);
        #pragma unroll
        for (int t = 0; t < 2; ++t) {
            uint4v bw;
            bw[0] = hi ? Sw[4 * t + 2] : W[4 * t + 0];
            bw[1] = hi ? Sw[4 * t + 3] : W[4 * t + 1];
            bw[2] = hi ? W[4 * t + 2] : Sw[4 * t + 0];
            bw[3] = hi ? W[4 * t + 3] : Sw[4 * t + 1];
            short8 pf = __builtin_bit_cast(short8, bw);
            o0 = MFMA32(cv[t], pf, o0);
            o1 = MFMA32(cv[2 + t], pf, o1);
        }
        __builtin_amdgcn_s_setprio(0);
    };

    for (int it2 = 0; it2 < 32; it2 += 2) {
        step(kAh, kAl, vA, kBh, kBl, vB, it2);
        step(kBh, kBl, vB, kAh, kAl, vA, it2 + 1);
    }

    // merge the two k-halves
    if (kh == 1) {
        float* mp = &mrg[lane][0];
        mp[0] = m_run; mp[1] = l_run;
        #pragma unroll
        for (int i = 0; i < 16; ++i) { mp[2 + i] = o0[i]; mp[18 + i] = o1[i]; }
    }
    __syncthreads();
    if (kh == 0) {
        const float* mp = &mrg[lane][0];
        float m2 = mp[0], l2 = mp[1];
        float ms = fmaxf(m_run, m2);
        float a1 = __expf(m_run - ms);
        float a2 = __expf(m2 - ms);
        float lt = l_run * a1 + l2 * a2;
        lt += __shfl_xor(lt, 32);
        float inv = 1.0f / lt;
        // ctx in A-fragment-tile order. Full row = b*2048 + q -> rt = b*32 + (q>>6)
        const int rt = b * 32 + (q >> 6), ii = (q >> 4) & 3, li2 = q & 15;
        const long baseA = ((long)(rt * 16 + 2 * h) * 4 + ii) * 512 + li2 * 8 + 4 * hi;
        #pragma unroll
        for (int a = 0; a < 4; ++a) {
            us4 w0, w1;
            #pragma unroll
            for (int c = 0; c < 4; ++c) {
                w0[c] = f2bf((o0[4 * a + c] * a1 + mp[2 + 4 * a + c] * a2) * inv);
                w1[c] = f2bf((o1[4 * a + c] * a1 + mp[18 + 4 * a + c] * a2) * inv);
            }
            *reinterpret_cast<us4*>(ctx + baseA + a * 128) = w0;
            *reinterpret_cast<us4*>(ctx + baseA + 2048 + a * 128) = w1;
        }
    }

    // fused position_bias write (b==0 blocks): 32 rows x 2048 f32 from lb.
    if (b == 0) {
        float* ob = outb + ((long)h * 2048 + q0) * 2048;
        #pragma unroll 4
        for (int c = 0; c < 64; ++c) {
            int chunk = c * 128 + tid;
            int r = chunk >> 8;                  // 256 chunks of 8 per row
            int k8 = (chunk & 255) * 8;
            const float* src = &lb[k8 - r + 31];
            f32x8 w;
            #pragma unroll
            for (int i = 0; i < 8; ++i) w[i] = src[i];
            *reinterpret_cast<f32x8*>(ob + (long)r * 2048 + k8) = w;
        }
    }
}

// ---------- output projection: ctx(tiles)[4096x512] @ Wo(tiles) -> d_out (f32) ----------
__global__ __launch_bounds__(256) void k_oproj(const unsigned short* __restrict__ ctx,
                                               const unsigned short* __restrict__ wot,
                                               float* __restrict__ outp) {
    const int wgid = blockIdx.x;            // 128 = 32 mt * 4 nt
    const int nt = wgid & 3, mt = wgid >> 2;
    const int tid = threadIdx.x, wv = tid >> 6, lane = tid & 63;
    const int wr = wv >> 1, wc = wv & 1;
    const int g = lane >> 4, li = lane & 15;
    const int m0 = mt * 128 + wr * 64;
    const int n0 = nt * 128 + wc * 64;
    const int rt2 = m0 >> 6, ntile = n0 >> 6;

    f32x4 zf = {0.f, 0.f, 0.f, 0.f};
    f32x4 acc[4][4];
    #pragma unroll
    for (int i = 0; i < 4; ++i)
        #pragma unroll
        for (int j = 0; j < 4; ++j) acc[i][j] = zf;

    for (int ks = 0; ks < 512; ks += 32) {
        const int kt = ks >> 5;
        const long abase = (long)(rt2 * 16 + kt) * 2048 + lane * 8;
        const long bbase = (long)(ntile * 16 + kt) * 2048 + lane * 8;
        short8 af[4], bf[4];
        #pragma unroll
        for (int i = 0; i < 4; ++i) {
            af[i] = *reinterpret_cast<const short8*>(ctx + abase + i * 512);
            bf[i] = *reinterpret_cast<const short8*>(wot + bbase + i * 512);
        }
        #pragma unroll
        for (int i = 0; i < 4; ++i)
            #pragma unroll
            for (int j = 0; j < 4; ++j)
                acc[i][j] = MFMA16(af[i], bf[j], acc[i][j]);
    }
    #pragma unroll
    for (int i = 0; i < 4; ++i) {
        int rowb = m0 + i * 16 + g * 4;
        #pragma unroll
        for (int j = 0; j < 4; ++j) {
            int col = n0 + j * 16 + li;
            #pragma unroll
            for (int r = 0; r < 4; ++r)
                outp[(long)(rowb + r) * 512 + col] = acc[i][j][r];
        }
    }
}

// ---------- launch ----------
extern "C" void kernel_launch(void* const* d_in, const int* in_sizes, int n_in,
                              void* d_out, int out_size, void* d_ws, size_t ws_size,
                              hipStream_t stream) {
    const float* hidden = (const float*)d_in[0];
    const float* Wq = (const float*)d_in[1];
    const float* Wk = (const float*)d_in[2];
    const float* Wv = (const float*)d_in[3];
    const float* Wo = (const float*)d_in[4];
    const float* emb = (const float*)d_in[5];
    float* out = (float*)d_out;

    char* ws = (char*)d_ws;
    size_t off = 0;
    auto alloc = [&](size_t bytes) { char* p = ws + off; off += (bytes + 255) & ~(size_t)255; return p; };

    unsigned short* hid_hi = (unsigned short*)alloc(4096ull * 512 * 2);   // htiles hi
    unsigned short* hid_lo = (unsigned short*)alloc(4096ull * 512 * 2);   // htiles lo
    unsigned short* wqthi  = (unsigned short*)alloc(512ull * 512 * 2);    // wtiles
    unsigned short* wqtlo  = (unsigned short*)alloc(512ull * 512 * 2);
    unsigned short* wkthi  = (unsigned short*)alloc(512ull * 512 * 2);
    unsigned short* wktlo  = (unsigned short*)alloc(512ull * 512 * 2);
    unsigned short* wvt    = (unsigned short*)alloc(512ull * 512 * 2);    // wtiles (V)
    unsigned short* wot    = (unsigned short*)alloc(512ull * 512 * 2);    // wtiles (O)
    float*          biasT  = (float*)alloc(8ull * 4096 * 4);
    unsigned short* q_hi   = (unsigned short*)alloc(4096ull * 512 * 2);
    unsigned short* q_lo   = (unsigned short*)alloc(4096ull * 512 * 2);
    unsigned short* ktiles = (unsigned short*)alloc(16ull * 64 * 8 * 512 * 2);  // 8 MB
    unsigned short* vtiles = (unsigned short*)alloc(16ull * 64 * 4 * 512 * 2);  // 4 MB
    unsigned short* ctx    = (unsigned short*)alloc(4096ull * 512 * 2);         // ctx tiles

    k_prep_hidden<<<512, 256, 0, stream>>>(hidden, hid_hi, hid_lo);
    k_prep_w<<<256, 256, 0, stream>>>(Wq, Wk, Wv, Wo, wqthi, wqtlo, wkthi, wktlo, wvt, wot);
    k_prep_bias<<<128, 256, 0, stream>>>(emb, biasT);
    k_proj<<<384, 256, 0, stream>>>(hid_hi, hid_lo, wqthi, wqtlo, wkthi, wktlo, wvt,
                                    q_hi, q_lo, ktiles, vtiles);
    k_attn<<<1024, 128, 0, stream>>>(q_hi, q_lo, ktiles, vtiles, biasT, ctx, out + 2097152);
    k_oproj<<<128, 256, 0, stream>>>(ctx, wot, out);
}

// Round 16
// 127.263 us; speedup vs baseline: 1.1433x; 1.1433x over previous
//
#include <hip/hip_runtime.h>

typedef __attribute__((ext_vector_type(8))) short short8;
typedef __attribute__((ext_vector_type(4))) float f32x4;
typedef __attribute__((ext_vector_type(16))) float f32x16;
typedef __attribute__((ext_vector_type(4))) float float4v;
typedef __attribute__((ext_vector_type(8))) float f32x8;
typedef __attribute__((ext_vector_type(4))) unsigned short us4;
typedef __attribute__((ext_vector_type(8))) unsigned short us8v;
typedef __attribute__((ext_vector_type(4))) unsigned int uint4v;

#define DEVI __device__ __forceinline__
#define MFMA16(a,b,c) __builtin_amdgcn_mfma_f32_16x16x32_bf16((a),(b),(c),0,0,0)
#define MFMA32(a,b,c) __builtin_amdgcn_mfma_f32_32x32x16_bf16((a),(b),(c),0,0,0)

// ---------- helpers ----------
DEVI unsigned short f2bf(float x) {            // f32 -> bf16 bits, RNE
    unsigned u = __builtin_bit_cast(unsigned, x);
    u += 0x7FFFu + ((u >> 16) & 1u);
    return (unsigned short)(u >> 16);
}
DEVI float bf2f(unsigned short b) {
    return __builtin_bit_cast(float, ((unsigned)b) << 16);
}
DEVI unsigned cvt_pk_bf16(float lo, float hi) {  // lo -> low16, hi -> high16 (RNE)
    unsigned r;
    asm("v_cvt_pk_bf16_f32 %0, %1, %2" : "=v"(r) : "v"(lo), "v"(hi));
    return r;
}

// ---------- prep: hidden f32 -> bf16 hi/lo in MFMA-fragment tile order ----------
// htiles[rt 0..63][kt 0..15][i 0..3][lane 0..63][8]:
//   content = hidden[rt*64 + i*16 + (lane&15)][kt*32 + (lane>>4)*8 + j]
__global__ __launch_bounds__(256) void k_prep_hidden(const float* __restrict__ hid,
                                                     unsigned short* __restrict__ hh,
                                                     unsigned short* __restrict__ hl) {
    __shared__ float tile[64][65];
    const int bid = blockIdx.x;                 // 512 = 64 rt x 8 ct
    const int rt = bid >> 3, ct = bid & 7;
    const int t = threadIdx.x;
    const int r = t >> 2, cc = (t & 3) << 4;
    const float* sp = hid + (long)(rt * 64 + r) * 512 + ct * 64 + cc;
    #pragma unroll
    for (int j = 0; j < 16; j += 4) {
        float4v v = *reinterpret_cast<const float4v*>(sp + j);
        tile[r][cc + j + 0] = v[0];
        tile[r][cc + j + 1] = v[1];
        tile[r][cc + j + 2] = v[2];
        tile[r][cc + j + 3] = v[3];
    }
    __syncthreads();
    #pragma unroll
    for (int s = 0; s < 2; ++s) {
        int slot = t * 2 + s;                   // 0..511 -> (ktl, i, lane)
        int lane = slot & 63, i = (slot >> 6) & 3, ktl = slot >> 8;
        int ri = i * 16 + (lane & 15);
        int kc = ktl * 32 + (lane >> 4) * 8;
        us8v hv, lv;
        #pragma unroll
        for (int j = 0; j < 8; ++j) {
            float x = tile[ri][kc + j];
            unsigned short hb = f2bf(x);
            hv[j] = hb; lv[j] = f2bf(x - bf2f(hb));
        }
        long o = ((long)(rt * 16 + ct * 2 + ktl) * 4 + i) * 512 + lane * 8;
        *reinterpret_cast<us8v*>(hh + o) = hv;
        *reinterpret_cast<us8v*>(hl + o) = lv;
    }
}

// ---------- prep: transpose weights; ALL mats in fragment-tile order ----------
// wtiles[nt 0..7][kt 0..15][jj 0..3][lane][8]:
//   content = W^T[nt*64 + jj*16 + (lane&15)][kt*32 + (lane>>4)*8 + j]
__global__ __launch_bounds__(256) void k_prep_w(const float* __restrict__ wq, const float* __restrict__ wk,
                                                const float* __restrict__ wvp, const float* __restrict__ wo,
                                                unsigned short* __restrict__ wqthi, unsigned short* __restrict__ wqtlo,
                                                unsigned short* __restrict__ wkthi, unsigned short* __restrict__ wktlo,
                                                unsigned short* __restrict__ wvt, unsigned short* __restrict__ wot) {
    __shared__ float tile[64][65];
    const int bid = blockIdx.x;                 // 256 = 4 mats x 64 tiles
    const int mat = bid >> 6, t6 = bid & 63;
    const int tr = t6 >> 3, tc = t6 & 7;        // source tile coords: [k-tile][n-tile]
    const float* src = mat == 0 ? wq : mat == 1 ? wk : mat == 2 ? wvp : wo;
    const int t = threadIdx.x;
    const int r = t >> 2, cc = (t & 3) << 4;
    const float* sp = src + (long)(tr * 64 + r) * 512 + tc * 64 + cc;
    #pragma unroll
    for (int j = 0; j < 16; j += 4) {
        float4v v = *reinterpret_cast<const float4v*>(sp + j);
        tile[r][cc + j + 0] = v[0];
        tile[r][cc + j + 1] = v[1];
        tile[r][cc + j + 2] = v[2];
        tile[r][cc + j + 3] = v[3];
    }
    __syncthreads();
    // thread owns n = tc*64 + r ; k = tr*64 + cc + 0..16
    us8v h0, h1, l0, l1;
    #pragma unroll
    for (int j = 0; j < 8; ++j) {
        float x = tile[cc + j][r];
        unsigned short hb = f2bf(x);
        h0[j] = hb; l0[j] = f2bf(x - bf2f(hb));
        float y = tile[cc + 8 + j][r];
        unsigned short hb2 = f2bf(y);
        h1[j] = hb2; l1[j] = f2bf(y - bf2f(hb2));
    }
    const int jj = r >> 4, li = r & 15;
    const int kt = (tr * 64 + cc) >> 5;
    const int g0 = (cc >> 3) & 3;           // 0 or 2
    const long bse = ((long)((tc * 16 + kt) * 4 + jj)) * 512;
    const long o0 = bse + (g0 * 16 + li) * 8;
    const long o1 = bse + ((g0 + 1) * 16 + li) * 8;
    if (mat <= 1) {
        unsigned short* oh = mat ? wkthi : wqthi;
        unsigned short* ol = mat ? wktlo : wqtlo;
        *reinterpret_cast<us8v*>(oh + o0) = h0;
        *reinterpret_cast<us8v*>(oh + o1) = h1;
        *reinterpret_cast<us8v*>(ol + o0) = l0;
        *reinterpret_cast<us8v*>(ol + o1) = l1;
    } else {
        unsigned short* oh = mat == 2 ? wvt : wot;
        *reinterpret_cast<us8v*>(oh + o0) = h0;
        *reinterpret_cast<us8v*>(oh + o1) = h1;
    }
}

// ---------- prep: bias table biasT[h][rel+2047] ----------
DEVI int bucket_large(int a) {   // exact integer thresholds of 8+floor(2*log2(a/8)), clamp 15
    if (a < 12) return 8;
    if (a < 16) return 9;
    if (a < 23) return 10;
    if (a < 32) return 11;
    if (a < 46) return 12;
    if (a < 64) return 13;
    if (a < 91) return 14;
    return 15;
}
__global__ __launch_bounds__(256) void k_prep_bias(const float* __restrict__ emb, float* __restrict__ biasT) {
    int t = blockIdx.x * 256 + threadIdx.x;
    if (t >= 8 * 4095) return;
    int h = t / 4095;
    int idx = t - h * 4095;
    int rel = idx - 2047;                // rel = k - q
    int a = rel < 0 ? -rel : rel;
    int bucket = (rel > 0 ? 16 : 0) + (a < 8 ? a : bucket_large(a));
    biasT[h * 4096 + idx] = emb[bucket * 8 + h];
}

// ---------- fused QKV projection; fragment-tiled A/B loads, K/V fragment-tile outputs ----------
__global__ __launch_bounds__(256) void k_proj(const unsigned short* __restrict__ hh,
                                              const unsigned short* __restrict__ hl,
                                              const unsigned short* __restrict__ wqthi, const unsigned short* __restrict__ wqtlo,
                                              const unsigned short* __restrict__ wkthi, const unsigned short* __restrict__ wktlo,
                                              const unsigned short* __restrict__ wvt,
                                              unsigned short* __restrict__ q_hi, unsigned short* __restrict__ q_lo,
                                              unsigned short* __restrict__ ktiles,
                                              unsigned short* __restrict__ vtiles) {
    // XCD-aware swizzle (T1): 384 = 8 XCDs x 48 consecutive logical blocks
    const int wgid = (blockIdx.x & 7) * 48 + (blockIdx.x >> 3);
    const int nt = wgid % 12, mt = wgid / 12;
    const int sec = nt >> 2;                // 0:Q 1:K 2:V
    const bool isv = (sec == 2);
    const int tid = threadIdx.x, wv = tid >> 6, lane = tid & 63;
    const int wr = wv >> 1, wc = wv & 1;
    const int g = lane >> 4, li = lane & 15;
    const int m0 = mt * 128 + wr * 64;
    const int n0 = (nt & 3) * 128 + wc * 64;    // col within section [0,512)
    const unsigned short* bh_ = (sec == 0) ? wqthi : (sec == 1) ? wkthi : wvt;
    const unsigned short* bl_ = (sec == 0) ? wqtlo : wktlo;
    const int rt2 = m0 >> 6;                 // A row-tile
    const int ntile = n0 >> 6;               // B n-tile within section

    f32x4 zf = {0.f, 0.f, 0.f, 0.f};
    f32x4 acc[4][4];
    #pragma unroll
    for (int i = 0; i < 4; ++i)
        #pragma unroll
        for (int j = 0; j < 4; ++j) acc[i][j] = zf;

    for (int ks = 0; ks < 512; ks += 32) {
        const int kt = ks >> 5;
        const long abase = ((long)(rt2 * 16 + kt) * 4) * 512 + lane * 8;
        const long bbase = ((long)(ntile * 16 + kt) * 4) * 512 + lane * 8;
        short8 ah[4], al[4], bhf[4], blf[4];
        #pragma unroll
        for (int i = 0; i < 4; ++i) {
            ah[i] = *reinterpret_cast<const short8*>(hh + abase + i * 512);
            if (!isv) al[i] = *reinterpret_cast<const short8*>(hl + abase + i * 512);
            bhf[i] = *reinterpret_cast<const short8*>(bh_ + bbase + i * 512);
            if (!isv) blf[i] = *reinterpret_cast<const short8*>(bl_ + bbase + i * 512);
        }
        #pragma unroll
        for (int i = 0; i < 4; ++i)
            #pragma unroll
            for (int j = 0; j < 4; ++j) {
                acc[i][j] = MFMA16(ah[i], bhf[j], acc[i][j]);
                if (!isv) {
                    acc[i][j] = MFMA16(ah[i], blf[j], acc[i][j]);
                    acc[i][j] = MFMA16(al[i], bhf[j], acc[i][j]);
                }
            }
    }

    if (sec == 0) {
        #pragma unroll
        for (int i = 0; i < 4; ++i) {
            int rowb = m0 + i * 16 + g * 4;
            #pragma unroll
            for (int j = 0; j < 4; ++j) {
                int col = n0 + j * 16 + li;
                #pragma unroll
                for (int r = 0; r < 4; ++r) {
                    float x = acc[i][j][r];
                    unsigned short hb = f2bf(x);
                    long o = (long)(rowb + r) * 512 + col;
                    q_hi[o] = hb;
                    q_lo[o] = f2bf(x - bf2f(hb));
                }
            }
        }
    } else if (sec == 1) {
        #pragma unroll
        for (int i = 0; i < 4; ++i) {
            int rowb = m0 + i * 16 + g * 4;
            #pragma unroll
            for (int j = 0; j < 4; ++j) {
                int col = n0 + j * 16 + li;
                int h2 = col >> 6, d = col & 63;
                int ds2 = d >> 4, j2 = d & 7, lhalf = (d >> 3) & 1;
                #pragma unroll
                for (int r = 0; r < 4; ++r) {
                    int srow = rowb + r;
                    int bloc = srow >> 11, k = srow & 2047;
                    long base = (long)((bloc * 8 + h2) * 64 + (k >> 5)) * 4096
                              + (((k & 31) | (lhalf << 5)) * 8 + j2);
                    float x = acc[i][j][r];
                    unsigned short hb = f2bf(x);
                    ktiles[base + ds2 * 512] = hb;
                    ktiles[base + (4 + ds2) * 512] = f2bf(x - bf2f(hb));
                }
            }
        }
    } else {
        #pragma unroll
        for (int i = 0; i < 4; ++i) {
            int rowb = m0 + i * 16 + g * 4;      // 4 consecutive k, same tile/half
            int bloc = rowb >> 11, k = rowb & 2047;
            int kt = k >> 5, t = (k >> 4) & 1, lhalf = (k >> 3) & 1, j0 = k & 7;
            #pragma unroll
            for (int j = 0; j < 4; ++j) {
                int col = n0 + j * 16 + li;
                int h2 = col >> 6, d = col & 63;
                int dblk = d >> 5;
                us4 w;
                #pragma unroll
                for (int r = 0; r < 4; ++r) w[r] = f2bf(acc[i][j][r]);
                long off2 = (long)((bloc * 8 + h2) * 64 + kt) * 2048
                          + (dblk * 2 + t) * 512 + (((d & 31) | (lhalf << 5)) * 8 + j0);
                *reinterpret_cast<us4*>(vtiles + off2) = w;
            }
        }
    }
}

// ---------- flash attention + fused position_bias writer ----------
// grid 1024 = 16 bh * 64 q-tiles(32 rows). block 128 = 2 waves: kh = k-half.
// Balanced XCD swizzle: XCD x owns bh {x, 8+x} -> K/V 1.5MB fits L2 AND bias
// writers (b==0) are spread across all 8 XCDs.
__global__ __launch_bounds__(128) void k_attn(const unsigned short* __restrict__ qhi,
                                              const unsigned short* __restrict__ qlo,
                                              const unsigned short* __restrict__ ktiles,
                                              const unsigned short* __restrict__ vtiles,
                                              const float* __restrict__ biasT,
                                              unsigned short* __restrict__ ctx,
                                              float* __restrict__ outb) {
    __shared__ float lb[2080];
    __shared__ float mrg[64][34];
    const int xcd = blockIdx.x & 7, lidx = blockIdx.x >> 3;   // lidx 0..127
    const int bh = ((lidx >> 6) << 3) | xcd;                  // b = lidx>>6, h = xcd
    const int qt = lidx & 63;
    const int b = bh >> 3, h = bh & 7;
    const int tid = threadIdx.x;
    const int kh = tid >> 6, lane = tid & 63;
    const int ql_ = lane & 31, hi = lane >> 5;
    const int q0 = qt * 32;

    // bias window: lb[i] = biasT[h][2016 - q0 + i]; in-loop index = k - ql_ + 31
    for (int i = tid; i < 2080; i += 128) lb[i] = biasT[h * 4096 + (2016 - q0) + i];
    __syncthreads();

    const int q = q0 + ql_;
    const long rowQ = (long)(b * 2048 + q) * 512 + h * 64 + hi * 8;
    short8 qfh[4], qfl[4];
    #pragma unroll
    for (int ds = 0; ds < 4; ++ds) {
        qfh[ds] = *reinterpret_cast<const short8*>(qhi + rowQ + ds * 16);
        qfl[ds] = *reinterpret_cast<const short8*>(qlo + rowQ + ds * 16);
    }
    const int kbeg = kh * 1024;
    const unsigned short* ktb = ktiles + ((long)bh * 64 + (kbeg >> 5)) * 4096;
    const unsigned short* vtb = vtiles + ((long)bh * 64 + (kbeg >> 5)) * 2048;

    f32x16 o0, o1;
    #pragma unroll
    for (int i = 0; i < 16; ++i) { o0[i] = 0.f; o1[i] = 0.f; }
    float m_run = -__builtin_inff(), l_run = 0.f;

    // register double buffers (prefetch tile 0)
    short8 kAh[4], kAl[4], kBh[4], kBl[4], vA[4], vB[4];
    #pragma unroll
    for (int ds = 0; ds < 4; ++ds) {
        kAh[ds] = *reinterpret_cast<const short8*>(ktb + ds * 512 + lane * 8);
        kAl[ds] = *reinterpret_cast<const short8*>(ktb + (4 + ds) * 512 + lane * 8);
    }
    #pragma unroll
    for (int i = 0; i < 4; ++i)
        vA[i] = *reinterpret_cast<const short8*>(vtb + i * 512 + lane * 8);

    auto step = [&](short8 (&ckh)[4], short8 (&ckl)[4], short8 (&cv)[4],
                    short8 (&nkh)[4], short8 (&nkl)[4], short8 (&nv)[4], int it) {
        // QK^T (two independent chains, pure reassociation)
        f32x16 ssA, ssB;
        #pragma unroll
        for (int i = 0; i < 16; ++i) { ssA[i] = 0.f; ssB[i] = 0.f; }
        __builtin_amdgcn_s_setprio(1);
        #pragma unroll
        for (int ds = 0; ds < 4; ++ds) {
            ssA = MFMA32(ckh[ds], qfh[ds], ssA);
            ssB = MFMA32(ckh[ds], qfl[ds], ssB);
        }
        #pragma unroll
        for (int ds = 0; ds < 4; ++ds)
            ssA = MFMA32(ckl[ds], qfh[ds], ssA);
        __builtin_amdgcn_s_setprio(0);
        // prefetch next tile (coalesced 1KB bursts; guarded re-read on last iter)
        const long ko = (it + 1 < 32) ? (long)(it + 1) * 4096 : (long)it * 4096;
        const long vo = (it + 1 < 32) ? (long)(it + 1) * 2048 : (long)it * 2048;
        #pragma unroll
        for (int ds = 0; ds < 4; ++ds) {
            nkh[ds] = *reinterpret_cast<const short8*>(ktb + ko + ds * 512 + lane * 8);
            nkl[ds] = *reinterpret_cast<const short8*>(ktb + ko + (4 + ds) * 512 + lane * 8);
        }
        #pragma unroll
        for (int i = 0; i < 4; ++i)
            nv[i] = *reinterpret_cast<const short8*>(vtb + vo + i * 512 + lane * 8);
        // bias + row softmax (row = q, all in-lane except one hi-swap)
        const int k0 = kbeg + it * 32;
        const int ib = k0 - ql_ + 31 + 4 * hi;
        float s[16];
        #pragma unroll
        for (int r = 0; r < 16; ++r)
            s[r] = (ssA[r] + ssB[r]) + lb[ib + (r & 3) + 8 * (r >> 2)];
        // max tree (depth 4)
        float t0 = fmaxf(s[0], s[1]), t1 = fmaxf(s[2], s[3]), t2 = fmaxf(s[4], s[5]), t3 = fmaxf(s[6], s[7]);
        float t4 = fmaxf(s[8], s[9]), t5 = fmaxf(s[10], s[11]), t6 = fmaxf(s[12], s[13]), t7 = fmaxf(s[14], s[15]);
        float u0 = fmaxf(t0, t1), u1 = fmaxf(t2, t3), u2 = fmaxf(t4, t5), u3 = fmaxf(t6, t7);
        float mx = fmaxf(fmaxf(u0, u1), fmaxf(u2, u3));
        mx = fmaxf(mx, __shfl_xor(mx, 32));
        bool grown = mx > m_run;
        float mnew = fmaxf(m_run, mx);
        float scale = __expf(m_run - mnew);
        float p[16];
        #pragma unroll
        for (int r = 0; r < 16; ++r) p[r] = __expf(s[r] - mnew);
        // pack via cvt_pk (RNE); denominator from the SAME rounded bits
        unsigned W[8];
        float ps[8];
        #pragma unroll
        for (int r2 = 0; r2 < 8; ++r2) {
            unsigned w = cvt_pk_bf16(p[2 * r2], p[2 * r2 + 1]);
            W[r2] = w;
            float plo = __builtin_bit_cast(float, w << 16);
            float phi = __builtin_bit_cast(float, w & 0xFFFF0000u);
            ps[r2] = plo + phi;
        }
        float psum = ((ps[0] + ps[1]) + (ps[2] + ps[3])) + ((ps[4] + ps[5]) + (ps[6] + ps[7]));
        l_run = l_run * scale + psum;
        m_run = mnew;
        // defer-rescale: when no row max grew, scale == 1.0 exactly -> skip is bit-identical
        if (__any(grown)) {
            #pragma unroll
            for (int i = 0; i < 16; ++i) { o0[i] *= scale; o1[i] *= scale; }
        }
        unsigned Sw[8];
        #pragma unroll
        for (int r2 = 0; r2 < 8; ++r2) Sw[r2] = __shfl_xor(W[r2], 32);
        __builtin_amdgcn_s_setprio(1);
        #pragma unroll
        for (int t = 0; t < 2; ++t) {
            uint4v bw;
            bw[0] = hi ? Sw[4 * t + 2] : W[4 * t + 0];
            bw[1] = hi ? Sw[4 * t + 3] : W[4 * t + 1];
            bw[2] = hi ? W[4 * t + 2] : Sw[4 * t + 0];
            bw[3] = hi ? W[4 * t + 3] : Sw[4 * t + 1];
            short8 pf = __builtin_bit_cast(short8, bw);
            o0 = MFMA32(cv[t], pf, o0);
            o1 = MFMA32(cv[2 + t], pf, o1);
        }
        __builtin_amdgcn_s_setprio(0);
    };

    for (int it2 = 0; it2 < 32; it2 += 2) {
        step(kAh, kAl, vA, kBh, kBl, vB, it2);
        step(kBh, kBl, vB, kAh, kAl, vA, it2 + 1);
    }

    // merge the two k-halves
    if (kh == 1) {
        float* mp = &mrg[lane][0];
        mp[0] = m_run; mp[1] = l_run;
        #pragma unroll
        for (int i = 0; i < 16; ++i) { mp[2 + i] = o0[i]; mp[18 + i] = o1[i]; }
    }
    __syncthreads();
    if (kh == 0) {
        const float* mp = &mrg[lane][0];
        float m2 = mp[0], l2 = mp[1];
        float ms = fmaxf(m_run, m2);
        float a1 = __expf(m_run - ms);
        float a2 = __expf(m2 - ms);
        float lt = l_run * a1 + l2 * a2;
        lt += __shfl_xor(lt, 32);
        float inv = 1.0f / lt;
        // ctx in A-fragment-tile order. Full row = b*2048 + q -> rt = b*32 + (q>>6)
        const int rt = b * 32 + (q >> 6), ii = (q >> 4) & 3, li2 = q & 15;
        const long baseA = ((long)(rt * 16 + 2 * h) * 4 + ii) * 512 + li2 * 8 + 4 * hi;
        #pragma unroll
        for (int a = 0; a < 4; ++a) {
            us4 w0, w1;
            #pragma unroll
            for (int c = 0; c < 4; ++c) {
                w0[c] = f2bf((o0[4 * a + c] * a1 + mp[2 + 4 * a + c] * a2) * inv);
                w1[c] = f2bf((o1[4 * a + c] * a1 + mp[18 + 4 * a + c] * a2) * inv);
            }
            *reinterpret_cast<us4*>(ctx + baseA + a * 128) = w0;
            *reinterpret_cast<us4*>(ctx + baseA + 2048 + a * 128) = w1;
        }
    }

    // fused position_bias write (b==0 blocks): 32 rows x 2048 f32, source = global
    // biasT (L2-resident, no LDS bank conflicts). Stores coalesced f32x8.
    if (b == 0) {
        float* ob = outb + ((long)h * 2048 + q0) * 2048;
        const float* bsrc = biasT + h * 4096 + 2047 - q0;
        #pragma unroll 4
        for (int c = 0; c < 64; ++c) {
            int chunk = c * 128 + tid;
            int r = chunk >> 8;                  // 256 chunks of 8 per row
            int k8 = (chunk & 255) * 8;
            const float* src = bsrc + (k8 - r);
            f32x8 w;
            #pragma unroll
            for (int i = 0; i < 8; ++i) w[i] = src[i];
            *reinterpret_cast<f32x8*>(ob + (long)r * 2048 + k8) = w;
        }
    }
}

// ---------- output projection: ctx(tiles)[4096x512] @ Wo(tiles) -> d_out (f32) ----------
__global__ __launch_bounds__(256) void k_oproj(const unsigned short* __restrict__ ctx,
                                               const unsigned short* __restrict__ wot,
                                               float* __restrict__ outp) {
    const int wgid = blockIdx.x;            // 128 = 32 mt * 4 nt
    const int nt = wgid & 3, mt = wgid >> 2;
    const int tid = threadIdx.x, wv = tid >> 6, lane = tid & 63;
    const int wr = wv >> 1, wc = wv & 1;
    const int g = lane >> 4, li = lane & 15;
    const int m0 = mt * 128 + wr * 64;
    const int n0 = nt * 128 + wc * 64;
    const int rt2 = m0 >> 6, ntile = n0 >> 6;

    f32x4 zf = {0.f, 0.f, 0.f, 0.f};
    f32x4 acc[4][4];
    #pragma unroll
    for (int i = 0; i < 4; ++i)
        #pragma unroll
        for (int j = 0; j < 4; ++j) acc[i][j] = zf;

    for (int ks = 0; ks < 512; ks += 32) {
        const int kt = ks >> 5;
        const long abase = (long)(rt2 * 16 + kt) * 2048 + lane * 8;
        const long bbase = (long)(ntile * 16 + kt) * 2048 + lane * 8;
        short8 af[4], bf[4];
        #pragma unroll
        for (int i = 0; i < 4; ++i) {
            af[i] = *reinterpret_cast<const short8*>(ctx + abase + i * 512);
            bf[i] = *reinterpret_cast<const short8*>(wot + bbase + i * 512);
        }
        #pragma unroll
        for (int i = 0; i < 4; ++i)
            #pragma unroll
            for (int j = 0; j < 4; ++j)
                acc[i][j] = MFMA16(af[i], bf[j], acc[i][j]);
    }
    #pragma unroll
    for (int i = 0; i < 4; ++i) {
        int rowb = m0 + i * 16 + g * 4;
        #pragma unroll
        for (int j = 0; j < 4; ++j) {
            int col = n0 + j * 16 + li;
            #pragma unroll
            for (int r = 0; r < 4; ++r)
                outp[(long)(rowb + r) * 512 + col] = acc[i][j][r];
        }
    }
}

// ---------- launch ----------
extern "C" void kernel_launch(void* const* d_in, const int* in_sizes, int n_in,
                              void* d_out, int out_size, void* d_ws, size_t ws_size,
                              hipStream_t stream) {
    const float* hidden = (const float*)d_in[0];
    const float* Wq = (const float*)d_in[1];
    const float* Wk = (const float*)d_in[2];
    const float* Wv = (const float*)d_in[3];
    const float* Wo = (const float*)d_in[4];
    const float* emb = (const float*)d_in[5];
    float* out = (float*)d_out;

    char* ws = (char*)d_ws;
    size_t off = 0;
    auto alloc = [&](size_t bytes) { char* p = ws + off; off += (bytes + 255) & ~(size_t)255; return p; };

    unsigned short* hid_hi = (unsigned short*)alloc(4096ull * 512 * 2);   // htiles hi
    unsigned short* hid_lo = (unsigned short*)alloc(4096ull * 512 * 2);   // htiles lo
    unsigned short* wqthi  = (unsigned short*)alloc(512ull * 512 * 2);    // wtiles
    unsigned short* wqtlo  = (unsigned short*)alloc(512ull * 512 * 2);
    unsigned short* wkthi  = (unsigned short*)alloc(512ull * 512 * 2);
    unsigned short* wktlo  = (unsigned short*)alloc(512ull * 512 * 2);
    unsigned short* wvt    = (unsigned short*)alloc(512ull * 512 * 2);    // wtiles (V)
    unsigned short* wot    = (unsigned short*)alloc(512ull * 512 * 2);    // wtiles (O)
    float*          biasT  = (float*)alloc(8ull * 4096 * 4);
    unsigned short* q_hi   = (unsigned short*)alloc(4096ull * 512 * 2);
    unsigned short* q_lo   = (unsigned short*)alloc(4096ull * 512 * 2);
    unsigned short* ktiles = (unsigned short*)alloc(16ull * 64 * 8 * 512 * 2);  // 8 MB
    unsigned short* vtiles = (unsigned short*)alloc(16ull * 64 * 4 * 512 * 2);  // 4 MB
    unsigned short* ctx    = (unsigned short*)alloc(4096ull * 512 * 2);         // ctx tiles

    k_prep_hidden<<<512, 256, 0, stream>>>(hidden, hid_hi, hid_lo);
    k_prep_w<<<256, 256, 0, stream>>>(Wq, Wk, Wv, Wo, wqthi, wqtlo, wkthi, wktlo, wvt, wot);
    k_prep_bias<<<128, 256, 0, stream>>>(emb, biasT);
    k_proj<<<384, 256, 0, stream>>>(hid_hi, hid_lo, wqthi, wqtlo, wkthi, wktlo, wvt,
                                    q_hi, q_lo, ktiles, vtiles);
    k_attn<<<1024, 128, 0, stream>>>(q_hi, q_lo, ktiles, vtiles, biasT, ctx, out + 2097152);
    k_oproj<<<128, 256, 0, stream>>>(ctx, wot, out);
}